// Round 2
// baseline (32.113 us; speedup 1.0000x reference)
//
#include <hip/hip_runtime.h>

#define HID 2048

typedef __attribute__((ext_vector_type(4))) float f32x4;

__device__ __forceinline__ float sigmoidf_(float x) {
    return 1.0f / (1.0f + __expf(-x));
}

// One 256-thread block per output neuron j in [0, HID).
// h0 = c0 = 0  =>  W_hh unused, f-gate dead:
//   h[j] = sigmoid(g_o) * tanh( sigmoid(g_i) * tanh(g_g) )
// with g_* = dot(W_ih[row_*], x) + b_ih[row_*] + b_hh[row_*]
template <int K>
__global__ __launch_bounds__(256) void lstm_layer_kernel(
    const float* __restrict__ W,     // [4*HID, K] fp32
    const float* __restrict__ b_ih,  // [4*HID] fp32
    const float* __restrict__ b_hh,  // [4*HID] fp32
    const float* __restrict__ x,     // [K] fp32
    float* __restrict__ h_out)       // [HID] fp32
{
    const int j    = blockIdx.x;
    const int t    = threadIdx.x;
    const int lane = t & 63;
    const int wv   = t >> 6;

    const float* ri = W + (size_t)j * K;                // i-gate row
    const float* rg = W + (size_t)(j + 2 * HID) * K;    // g-gate row
    const float* ro = W + (size_t)(j + 3 * HID) * K;    // o-gate row

    float ai = 0.f, ag = 0.f, ao = 0.f;

    #pragma unroll
    for (int c = 0; c < K / 1024; ++c) {
        const int off = c * 1024 + t * 4;               // 16B/lane, coalesced
        f32x4 xv = *reinterpret_cast<const f32x4*>(x  + off);
        f32x4 wi = *reinterpret_cast<const f32x4*>(ri + off);
        f32x4 wg = *reinterpret_cast<const f32x4*>(rg + off);
        f32x4 wo = *reinterpret_cast<const f32x4*>(ro + off);

        ai = fmaf(wi.x, xv.x, ai); ai = fmaf(wi.y, xv.y, ai);
        ai = fmaf(wi.z, xv.z, ai); ai = fmaf(wi.w, xv.w, ai);
        ag = fmaf(wg.x, xv.x, ag); ag = fmaf(wg.y, xv.y, ag);
        ag = fmaf(wg.z, xv.z, ag); ag = fmaf(wg.w, xv.w, ag);
        ao = fmaf(wo.x, xv.x, ao); ao = fmaf(wo.y, xv.y, ao);
        ao = fmaf(wo.z, xv.z, ao); ao = fmaf(wo.w, xv.w, ao);
    }

    // wave64 butterfly, then cross-wave via LDS
    #pragma unroll
    for (int m = 32; m > 0; m >>= 1) {
        ai += __shfl_xor(ai, m, 64);
        ag += __shfl_xor(ag, m, 64);
        ao += __shfl_xor(ao, m, 64);
    }

    __shared__ float red[3][4];
    if (lane == 0) { red[0][wv] = ai; red[1][wv] = ag; red[2][wv] = ao; }
    __syncthreads();

    if (t == 0) {
        const float gi = red[0][0] + red[0][1] + red[0][2] + red[0][3]
                       + b_ih[j]           + b_hh[j];
        const float gg = red[1][0] + red[1][1] + red[1][2] + red[1][3]
                       + b_ih[j + 2 * HID] + b_hh[j + 2 * HID];
        const float go = red[2][0] + red[2][1] + red[2][2] + red[2][3]
                       + b_ih[j + 3 * HID] + b_hh[j + 3 * HID];
        const float iv = sigmoidf_(gi);
        const float gv = tanhf(gg);
        const float ov = sigmoidf_(go);
        h_out[j] = ov * tanhf(iv * gv);                 // f*c0 == 0
    }
}

// out[0] = dot(fc_w, h) + fc_b   (OUT_DIM == 1), all fp32
__global__ __launch_bounds__(256) void fc_kernel(
    const float* __restrict__ fc_w,  // [HID]
    const float* __restrict__ fc_b,  // [1]
    const float* __restrict__ h,     // [HID]
    float* __restrict__ out)         // [1]
{
    const int t    = threadIdx.x;
    const int lane = t & 63;
    const int wv   = t >> 6;

    float acc = 0.f;
    #pragma unroll
    for (int c = 0; c < 2; ++c) {
        const int off = c * 1024 + t * 4;
        f32x4 w  = *reinterpret_cast<const f32x4*>(fc_w + off);
        f32x4 hv = *reinterpret_cast<const f32x4*>(h    + off);
        acc = fmaf(w.x, hv.x, acc); acc = fmaf(w.y, hv.y, acc);
        acc = fmaf(w.z, hv.z, acc); acc = fmaf(w.w, hv.w, acc);
    }

    #pragma unroll
    for (int m = 32; m > 0; m >>= 1) acc += __shfl_xor(acc, m, 64);

    __shared__ float red[4];
    if (lane == 0) red[wv] = acc;
    __syncthreads();
    if (t == 0) out[0] = red[0] + red[1] + red[2] + red[3] + fc_b[0];
}

extern "C" void kernel_launch(void* const* d_in, const int* in_sizes, int n_in,
                              void* d_out, int out_size, void* d_ws, size_t ws_size,
                              hipStream_t stream) {
    // setup_inputs() order (all fp32 on device; W_hh_* dead since h0=0):
    // 0:x 1:W_ih_0 2:W_hh_0 3:b_ih_0 4:b_hh_0
    // 5:W_ih_1 6:W_hh_1 7:b_ih_1 8:b_hh_1
    // 9:W_ih_2 10:W_hh_2 11:b_ih_2 12:b_hh_2
    // 13:fc_w 14:fc_b
    const float* x    = (const float*)d_in[0];
    const float* Wih0 = (const float*)d_in[1];
    const float* bih0 = (const float*)d_in[3];
    const float* bhh0 = (const float*)d_in[4];
    const float* Wih1 = (const float*)d_in[5];
    const float* bih1 = (const float*)d_in[7];
    const float* bhh1 = (const float*)d_in[8];
    const float* Wih2 = (const float*)d_in[9];
    const float* bih2 = (const float*)d_in[11];
    const float* bhh2 = (const float*)d_in[12];
    const float* fcw  = (const float*)d_in[13];
    const float* fcb  = (const float*)d_in[14];

    float* h1 = (float*)d_ws;        // [HID] fp32
    float* h2 = h1 + HID;
    float* h3 = h2 + HID;

    lstm_layer_kernel<1024><<<HID, 256, 0, stream>>>(Wih0, bih0, bhh0, x,  h1);
    lstm_layer_kernel<2048><<<HID, 256, 0, stream>>>(Wih1, bih1, bhh1, h1, h2);
    lstm_layer_kernel<2048><<<HID, 256, 0, stream>>>(Wih2, bih2, bhh2, h2, h3);
    fc_kernel<<<1, 256, 0, stream>>>(fcw, fcb, h3, (float*)d_out);
}